// Round 22
// baseline (507.352 us; speedup 1.0000x reference)
//
#include <hip/hip_runtime.h>
#include <stdint.h>

#define NN    200000
#define NE    100000
#define HD    128
#define EFD   64
#define NG    384

typedef unsigned long long u64;
typedef short bf16x8 __attribute__((ext_vector_type(8)));
typedef float f32x4  __attribute__((ext_vector_type(4)));

#define OFF_KEY   ((size_t)0)
#define OFF_CNT   ((size_t)1600000)
#define OFF_LIST  ((size_t)1600256)
#define OFF_UV    ((size_t)2400256)
#define OFF_HN    ((size_t)104800256)
#define OFF_A     ((size_t)117600256)
#define OFF_B     ((size_t)117608448)
#define OFF_C0    ((size_t)117616640)
#define OFF_WBF   ((size_t)117616896)
#define WS_NEED   ((size_t)118092032)

#define W1OFF 221184
#define GRUB  3128
#define LSTB  782

// GRU arena offsets (bytes): main loop Wsb 0..24K, Xsb 24..28K (inside the 32K
// W1 epilogue region); Mn2 32..48K; sn/bias parked at tail (survive epilogue).
#define AR_XSB   24576
#define AR_MN2   32768
#define AR_SNS   49152
#define AR_SNO   49408
#define AR_SNE   49664
#define AR_SNDT  49920
#define AR_BIAS  50176
#define AR_SIZE  52736

__device__ __forceinline__ float frcp(float x){ return __builtin_amdgcn_rcpf(x); }
__device__ __forceinline__ float sigf(float x){ return frcp(1.f + __expf(-x)); }
__device__ __forceinline__ float tanhf_(float x){ return 1.f - 2.f*frcp(__expf(2.f*x) + 1.f); }
__device__ __forceinline__ float4 ld4(const float* p){ return *reinterpret_cast<const float4*>(p); }

__device__ __forceinline__ short f2bf(float f){
  unsigned u = __float_as_uint(f);
  u += 0x7fffu + ((u>>16)&1u);
  return (short)(u>>16);
}
__device__ __forceinline__ unsigned cvtpk(float lo, float hi){
  unsigned r;
  asm("v_cvt_pk_bf16_f32 %0, %1, %2" : "=v"(r) : "v"(lo), "v"(hi));
  return r;
}
__device__ __forceinline__ void gl16(const void* g, void* l) {
  __builtin_amdgcn_global_load_lds(
      (const __attribute__((address_space(1))) void*)g,
      (__attribute__((address_space(3))) void*)l, 16, 0, 0);
}

__global__ void k_scatter(const int* __restrict__ src, const int* __restrict__ dst,
                          const int* __restrict__ t, u64* __restrict__ key) {
  int e = blockIdx.x*256 + threadIdx.x;
  if (e >= NE) return;
  u64 tt = (u64)(unsigned)(t[e] + 1);
  atomicMax(&key[src[e]], (tt<<18) | (u64)(unsigned)e);
  atomicMax(&key[dst[e]], (tt<<18) | (1ULL<<17) | (u64)(unsigned)e);
}

__global__ void k_compact(const u64* __restrict__ key, int* __restrict__ list,
                          int* __restrict__ count) {
  int n = blockIdx.x*256 + threadIdx.x;
  if (n >= NN) return;
  if (key[n] != 0ULL) { int p = atomicAdd(count, 1); list[p] = n; }
}

__global__ void k_pre(const float* __restrict__ W1, const float* __restrict__ W_sp,
                      const float* __restrict__ W_pp, const float* __restrict__ b_sp,
                      const float* __restrict__ b_pp, const float* __restrict__ b1,
                      float* __restrict__ A, float* __restrict__ B, float* __restrict__ c0)
{
  int tid = blockIdx.x*256 + threadIdx.x;
  if (tid < 2048) {
    int o = tid >> 5, j = tid & 31;
    float s = 0.f;
    for (int k = 0; k < 128; ++k) s = fmaf(W1[o*NG + k], W_sp[k*32 + j], s);
    A[tid] = s;
  } else if (tid < 4096) {
    int q = tid - 2048;
    int o = q >> 5, j = q & 31;
    float s = 0.f;
    for (int k = 0; k < 128; ++k)
      s = fmaf(W1[o*NG + 128 + k] + W1[o*NG + 256 + k], W_pp[k*32 + j], s);
    B[q] = s;
  } else if (tid < 4160) {
    int o = tid - 4096;
    float s = b1[o];
    for (int k = 0; k < 128; ++k) {
      s = fmaf(W1[o*NG + k], b_sp[k], s);
      s = fmaf(W1[o*NG + 128 + k] + W1[o*NG + 256 + k], b_pp[k], s);
    }
    c0[o] = s;
  }
}

// ---------- pre-convert weights to bf16 ----------
// Section 1: gate W chunks BK=32: [18][384 n][4 slots][8] (slot s holds k8=s^(n&3))
// Section 2: W1ab [128 r][16 slots][8] (slot s holds k8=s^(r&15))
__global__ void k_prew(const float* __restrict__ W_ih, const float* __restrict__ W_hh,
                       const float* __restrict__ W1, short* __restrict__ Wbf)
{
  int idx = blockIdx.x*256 + threadIdx.x;
  if (idx < 18*384*4) {
    int s  = idx & 3;
    int n  = (idx >> 2) % 384;
    int ch = idx / (384*4);
    int k8 = s ^ (n & 3);
    int k  = ch*32 + k8*8;
    short v[8];
    #pragma unroll
    for (int e = 0; e < 8; ++e) {
      int kk = k + e;
      float f = (kk < 448) ? W_ih[(size_t)n*448 + kk] : W_hh[(size_t)n*HD + (kk-448)];
      v[e] = f2bf(f);
    }
    *reinterpret_cast<bf16x8*>(Wbf + (size_t)ch*12288 + n*32 + s*8) =
        *reinterpret_cast<bf16x8*>(v);
  } else if (idx < 18*384*4 + 128*16) {
    int idx2 = idx - 18*384*4;
    int s = idx2 & 15, r = idx2 >> 4;
    int k8 = s ^ (r & 15);
    int k = k8*8;
    short v[8];
    #pragma unroll
    for (int e = 0; e < 8; ++e) {
      int kk = k + e;
      float f = (r < 64) ? W1[(size_t)r*NG + kk] : W1[(size_t)(r-64)*NG + 128 + kk];
      v[e] = f2bf(f);
    }
    *reinterpret_cast<bf16x8*>(Wbf + W1OFF + r*128 + s*8) =
        *reinterpret_cast<bf16x8*>(v);
  }
}

// ---------- FUSED GRU + LSTM: 512 thr, 3 blocks/CU; bid<LSTB -> LSTM ----------
__global__ __launch_bounds__(512, 3) void k_gl(
    const u64* __restrict__ key, const int* __restrict__ list, const int* __restrict__ count,
    const int* __restrict__ src, const int* __restrict__ dst, const int* __restrict__ t,
    const float* __restrict__ msg, const float* __restrict__ memory,
    const float* __restrict__ last_update,
    const float* __restrict__ w_t, const float* __restrict__ b_t,
    const short* __restrict__ Wbf, const float* __restrict__ b_ih,
    const float* __restrict__ b_hh, float* __restrict__ uv,
    const float* __restrict__ price, const float* __restrict__ W_ihl,
    const float* __restrict__ W_hhl, const float* __restrict__ b_ihl,
    const float* __restrict__ b_hhl, float* __restrict__ hn_out)
{
  __shared__ __align__(16) char lds[AR_SIZE];
  int bid = blockIdx.x;
  int tid = threadIdx.x;
  int wid = tid >> 6, lane = tid & 63;
  int lr = lane & 15, lk = lane >> 4;

  if (bid >= LSTB) {
    // ================= GRU role (BK=32, 18 phases) =================
    int g = bid - LSTB;
    short* Wsb   = reinterpret_cast<short*>(lds);            // 24KB (main loop)
    short* Xsb   = reinterpret_cast<short*>(lds + AR_XSB);   // 4KB
    short* Mn2   = reinterpret_cast<short*>(lds + AR_MN2);   // 16KB (epilogue)
    int*   sn_self  = reinterpret_cast<int*>(lds + AR_SNS);
    int*   sn_other = reinterpret_cast<int*>(lds + AR_SNO);
    int*   sn_e     = reinterpret_cast<int*>(lds + AR_SNE);
    float* sn_dt    = reinterpret_cast<float*>(lds + AR_SNDT);
    float* bias4    = reinterpret_cast<float*>(lds + AR_BIAS);

    int cnt = count[0];
    int base = g * 64;
    if (base >= cnt) return;

    if (tid < 64) {
      int idx = base + tid;
      int cl = idx < cnt ? idx : (cnt - 1);
      int n = list[cl];
      u64 k = key[n];
      int e   = (int)(k & 0x1FFFFULL);
      int isd = (int)((k >> 17) & 1ULL);
      sn_self[tid]  = n;
      sn_other[tid] = isd ? src[e] : dst[e];
      sn_e[tid]     = e;
      sn_dt[tid]    = (float)t[e] - last_update[n];
    }
    if (tid < 128) {
      int h = tid;
      bias4[h]       = b_ih[h]       + b_hh[h];
      bias4[128 + h] = b_ih[128 + h] + b_hh[128 + h];
      bias4[256 + h] = b_ih[256 + h];
      bias4[384 + h] = b_hh[256 + h];
    }
    __syncthreads();

    f32x4 aR[4], aZ[4], aNX[4], aNM[4];
    #pragma unroll
    for (int mt = 0; mt < 4; ++mt) { aR[mt] = (f32x4)0.f; aZ[mt] = (f32x4)0.f;
                                     aNX[mt] = (f32x4)0.f; aNM[mt] = (f32x4)0.f; }

    int node4 = tid >> 2, k8s = tid & 3;   // staging coords (tid<256 stage)

    // W chunk order: pairs (c, c+14) share X chunk c (self k<128 == k>=448);
    // XST: X chunk to stage this phase (-1 reuse); chunks 10..13 are cos.
    constexpr int WCH[18] = {0,14, 1,15, 2,16, 3,17, 4,5,6,7,8,9,10,11,12,13};
    constexpr int XSTt[18] = {0,-1, 1,-1, 2,-1, 3,-1, 4,5,6,7,8,9,10,11,12,13};

    int hrow = wid*16 + lr;
    int swzH = (hrow & 3);

    #pragma unroll
    for (int p = 0; p < 18; ++p) {
      const int W = WCH[p];
      // W chunk: 1536 quads via gl16 (3 x 512)
      #pragma unroll
      for (int i = 0; i < 3; ++i) {
        int q = i*512 + tid;
        gl16(Wbf + (size_t)W*12288 + q*8, &Wsb[q*8]);
      }
      // X chunk: 256 quads, staged by tid<256 (JIT gather; 3 blocks/CU hide latency)
      int xc = XSTt[p];
      if (xc >= 0 && tid < 256) {
        float xf[8];
        if (xc <= 3) {
          const float* q = memory + (size_t)sn_self[node4]*HD + xc*32 + k8s*8;
          float4 a = ld4(q), b = ld4(q+4);
          xf[0]=a.x; xf[1]=a.y; xf[2]=a.z; xf[3]=a.w; xf[4]=b.x; xf[5]=b.y; xf[6]=b.z; xf[7]=b.w;
        } else if (xc <= 7) {
          const float* q = memory + (size_t)sn_other[node4]*HD + (xc-4)*32 + k8s*8;
          float4 a = ld4(q), b = ld4(q+4);
          xf[0]=a.x; xf[1]=a.y; xf[2]=a.z; xf[3]=a.w; xf[4]=b.x; xf[5]=b.y; xf[6]=b.z; xf[7]=b.w;
        } else if (xc <= 9) {
          const float* q = msg + (size_t)sn_e[node4]*EFD + (xc-8)*32 + k8s*8;
          float4 a = ld4(q), b = ld4(q+4);
          xf[0]=a.x; xf[1]=a.y; xf[2]=a.z; xf[3]=a.w; xf[4]=b.x; xf[5]=b.y; xf[6]=b.z; xf[7]=b.w;
        } else {
          int kk = (xc-10)*32 + k8s*8;
          float dt = sn_dt[node4];
          #pragma unroll
          for (int q = 0; q < 8; ++q) xf[q] = cosf(fmaf(dt, w_t[kk+q], b_t[kk+q]));
        }
        short xs[8];
        #pragma unroll
        for (int q = 0; q < 8; ++q) xs[q] = f2bf(xf[q]);
        *reinterpret_cast<bf16x8*>(&Xsb[node4*32 + ((k8s ^ (node4&3))<<3)]) =
            *reinterpret_cast<bf16x8*>(xs);
      }
      __syncthreads();

      {
        int so = (lk ^ swzH) << 3;
        bf16x8 bR = *reinterpret_cast<const bf16x8*>(&Wsb[(size_t)hrow*32 + so]);
        bf16x8 bZ = *reinterpret_cast<const bf16x8*>(&Wsb[(size_t)(128+hrow)*32 + so]);
        bf16x8 bN = *reinterpret_cast<const bf16x8*>(&Wsb[(size_t)(256+hrow)*32 + so]);
        #pragma unroll
        for (int mt = 0; mt < 4; ++mt) {
          int anode = mt*16 + lr;
          bf16x8 a = *reinterpret_cast<const bf16x8*>(&Xsb[anode*32 + ((lk ^ (anode&3))<<3)]);
          aR[mt] = __builtin_amdgcn_mfma_f32_16x16x32_bf16(a, bR, aR[mt], 0, 0, 0);
          aZ[mt] = __builtin_amdgcn_mfma_f32_16x16x32_bf16(a, bZ, aZ[mt], 0, 0, 0);
          if (W < 14) aNX[mt] = __builtin_amdgcn_mfma_f32_16x16x32_bf16(a, bN, aNX[mt], 0, 0, 0);
          else        aNM[mt] = __builtin_amdgcn_mfma_f32_16x16x32_bf16(a, bN, aNM[mt], 0, 0, 0);
        }
      }
      __syncthreads();
    }

    // stage W1ab (2048 quads, clobbers Wsb+Xsb; overlaps nonlinearity)
    #pragma unroll
    for (int i = 0; i < 4; ++i) {
      int q = i*512 + tid;
      gl16(Wbf + W1OFF + q*8, &Wsb[q*8]);
    }

    // GRU nonlinearity -> Mn2 bf16 A-frags
    {
      int h = hrow;
      int k8h = h >> 3, eh = h & 7;
      float br_ = bias4[h], bz_ = bias4[128+h], bnx_ = bias4[256+h], bnm_ = bias4[384+h];
      #pragma unroll
      for (int mt = 0; mt < 4; ++mt) {
        #pragma unroll
        for (int i = 0; i < 4; ++i) {
          int node = mt*16 + lk*4 + i;
          float r  = sigf(aR[mt][i] + br_);
          float z  = sigf(aZ[mt][i] + bz_);
          float nv = tanhf_(aNX[mt][i] + bnx_ + r*(aNM[mt][i] + bnm_));
          float m  = memory[(size_t)sn_self[node]*HD + h];
          Mn2[node*128 + ((k8h ^ (node&15))<<3) + eh] = f2bf((1.f - z)*nv + z*m);
        }
      }
    }
    __syncthreads();

    // uv = Mn @ W1ab^T via MFMA
    {
      int orow = wid*16 + lr;
      f32x4 acc2[4];
      #pragma unroll
      for (int mt = 0; mt < 4; ++mt) acc2[mt] = (f32x4)0.f;
      #pragma unroll
      for (int kf = 0; kf < 4; ++kf) {
        int k8 = kf*4 + lk;
        bf16x8 b = *reinterpret_cast<const bf16x8*>(&Wsb[orow*128 + ((k8 ^ (orow&15))<<3)]);
        #pragma unroll
        for (int mt = 0; mt < 4; ++mt) {
          int anode = mt*16 + lr;
          bf16x8 a = *reinterpret_cast<const bf16x8*>(&Mn2[anode*128 + ((k8 ^ (anode&15))<<3)]);
          acc2[mt] = __builtin_amdgcn_mfma_f32_16x16x32_bf16(a, b, acc2[mt], 0, 0, 0);
        }
      }
      #pragma unroll
      for (int mt = 0; mt < 4; ++mt) {
        #pragma unroll
        for (int i = 0; i < 4; ++i) {
          int node = mt*16 + lk*4 + i;
          if (base + node < cnt)
            uv[(size_t)sn_self[node]*128 + orow] = acc2[mt][i];
        }
      }
    }
  } else {
    // ================= LSTM role (block l = bid, 128 edges, 8 waves) =================
    int l = bid;
    short* Wb   = reinterpret_cast<short*>(lds);             // 8KB
    float* ps   = reinterpret_cast<float*>(lds + 8192);      // 25.6KB
    float* hbuf = reinterpret_cast<float*>(lds + 33792);     // 18.4KB

    {
      int base = tid * 8;
      #pragma unroll
      for (int q = 0; q < 4; ++q) {
        unsigned pk = cvtpk(W_hhl[base + q*2], W_hhl[base + q*2 + 1]);
        reinterpret_cast<unsigned*>(Wb)[tid*4 + q] = pk;
      }
    }
    int ebase = l * 128;
    int m = NE - ebase; if (m > 128) m = 128;
    for (int i = tid; i < 128*50; i += 512) {
      int r = i / 50, cidx = i % 50;
      int rr = r < m ? r : m - 1;
      ps[i] = price[(size_t)(ebase + rr)*50 + cidx];
    }
    __syncthreads();

    bf16x8 bw[8];
    float wih8[8], bias8[8];
    #pragma unroll
    for (int tI = 0; tI < 8; ++tI) {
      int row = tI*16 + lr;
      bw[tI] = *reinterpret_cast<const bf16x8*>(&Wb[row*32 + lk*8]);
      wih8[tI] = W_ihl[row];
      bias8[tI] = b_ihl[row] + b_hhl[row];
    }

    int we = wid * 16;
    float* hb = hbuf + wid*576;

    float c8[4][2];
    #pragma unroll
    for (int i = 0; i < 4; ++i) { c8[i][0] = 0.f; c8[i][1] = 0.f; }
    bf16x8 afrag = {0,0,0,0,0,0,0,0};

    #pragma unroll 1
    for (int s = 0; s < 50; ++s) {
      float xv[4];
      #pragma unroll
      for (int i = 0; i < 4; ++i) xv[i] = ps[(we + lk*4 + i)*50 + s];
      f32x4 acc[8];
      #pragma unroll
      for (int tI = 0; tI < 8; ++tI) {
        f32x4 ci;
        #pragma unroll
        for (int i = 0; i < 4; ++i) ci[i] = fmaf(xv[i], wih8[tI], bias8[tI]);
        acc[tI] = __builtin_amdgcn_mfma_f32_16x16x32_bf16(afrag, bw[tI], ci, 0, 0, 0);
      }
      #pragma unroll
      for (int i = 0; i < 4; ++i) {
        #pragma unroll
        for (int p = 0; p < 2; ++p) {
          float ei = __expf(-acc[0+p][i]);
          float ef = __expf(-acc[2+p][i]);
          float eg = __expf(2.f*acc[4+p][i]);
          float eo = __expf(-acc[6+p][i]);
          float di = 1.f + ei, df_ = 1.f + ef, dg = eg + 1.f, do_ = 1.f + eo;
          float m1 = di*df_, m2 = do_*dg;
          float R  = frcp(m1*m2);
          float ig = R*df_*m2;
          float fg = R*di*m2;
          float og = R*m1*dg;
          float gg = fmaf(-2.f, R*m1*do_, 1.f);
          c8[i][p] = fmaf(fg, c8[i][p], ig*gg);
          float th = 1.f - 2.f*frcp(__expf(2.f*c8[i][p]) + 1.f);
          hb[(lk*4 + i)*36 + p*16 + lr] = og*th;
        }
      }
      asm volatile("s_waitcnt lgkmcnt(0)" ::: "memory");
      float4 h0 = *reinterpret_cast<const float4*>(&hb[lr*36 + lk*8]);
      float4 h1 = *reinterpret_cast<const float4*>(&hb[lr*36 + lk*8 + 4]);
      unsigned pk_[4];
      pk_[0] = cvtpk(h0.x, h0.y);
      pk_[1] = cvtpk(h0.z, h0.w);
      pk_[2] = cvtpk(h1.x, h1.y);
      pk_[3] = cvtpk(h1.z, h1.w);
      afrag = *reinterpret_cast<bf16x8*>(pk_);
    }

    int e_g = ebase + we + lr;
    if (e_g < NE) {
      float4 h0 = *reinterpret_cast<const float4*>(&hb[lr*36 + lk*8]);
      float4 h1 = *reinterpret_cast<const float4*>(&hb[lr*36 + lk*8 + 4]);
      *reinterpret_cast<float4*>(hn_out + (size_t)e_g*32 + lk*8)     = h0;
      *reinterpret_cast<float4*>(hn_out + (size_t)e_g*32 + lk*8 + 4) = h1;
    }
  }
}

// ---------- fused output ----------
__global__ __launch_bounds__(256) void k_final(
    const int* __restrict__ src, const int* __restrict__ dst, const int* __restrict__ xst,
    const float* __restrict__ party, const float* __restrict__ state,
    const float* __restrict__ uv, const float* __restrict__ hn,
    const float* __restrict__ A, const float* __restrict__ B, const float* __restrict__ c0,
    const float* __restrict__ W2, const float* __restrict__ b2, float* __restrict__ out)
{
  __shared__ float As[2048], Bs[2048], c0s[64], W2s[64];
  int tid = threadIdx.x;
  for (int i = tid; i < 2048; i += 256) { As[i] = A[i]; Bs[i] = B[i]; }
  if (tid < 64) { c0s[tid] = c0[tid]; W2s[tid] = W2[tid]; }
  __syncthreads();
  int e = blockIdx.x*256 + tid;
  if (e >= NE) return;
  int s = src[e], d = dst[e];
  int p = xst[2*s], stt = xst[2*s + 1];
  float4 sf4[8], hv4[8];
  #pragma unroll
  for (int i = 0; i < 4; ++i) sf4[i]   = ld4(party + p*16 + i*4);
  #pragma unroll
  for (int i = 0; i < 4; ++i) sf4[4+i] = ld4(state + stt*16 + i*4);
  #pragma unroll
  for (int i = 0; i < 8; ++i) hv4[i] = ld4(hn + (size_t)e*32 + i*4);
  const float* urow = uv + (size_t)s*128;
  const float* vrow = uv + (size_t)d*128 + 64;
  float oacc = b2[0];
  #pragma unroll 4
  for (int o4 = 0; o4 < 16; ++o4) {
    float4 u4 = ld4(urow + o4*4);
    float4 v4 = ld4(vrow + o4*4);
    float4 cc = *reinterpret_cast<const float4*>(&c0s[o4*4]);
    float4 w2 = *reinterpret_cast<const float4*>(&W2s[o4*4]);
    float hh[4] = {u4.x+v4.x+cc.x, u4.y+v4.y+cc.y, u4.z+v4.z+cc.z, u4.w+v4.w+cc.w};
    #pragma unroll
    for (int oo = 0; oo < 4; ++oo) {
      int o = o4*4 + oo;
      float acc = hh[oo];
      #pragma unroll
      for (int j4 = 0; j4 < 8; ++j4) {
        float4 a = *reinterpret_cast<const float4*>(&As[o*32 + j4*4]);
        float4 b = *reinterpret_cast<const float4*>(&Bs[o*32 + j4*4]);
        float4 sfv = sf4[j4], hvv = hv4[j4];
        acc = fmaf(a.x,sfv.x, fmaf(a.y,sfv.y, fmaf(a.z,sfv.z, fmaf(a.w,sfv.w, acc))));
        acc = fmaf(b.x,hvv.x, fmaf(b.y,hvv.y, fmaf(b.z,hvv.z, fmaf(b.w,hvv.w, acc))));
      }
      float w2v = (oo==0) ? w2.x : (oo==1) ? w2.y : (oo==2) ? w2.z : w2.w;
      oacc = fmaf(w2v, fmaxf(acc, 0.f), oacc);
    }
  }
  out[e] = oacc;
}

extern "C" void kernel_launch(void* const* d_in, const int* in_sizes, int n_in,
                              void* d_out, int out_size, void* d_ws, size_t ws_size,
                              hipStream_t stream) {
  const int*   src   = (const int*)d_in[0];
  const int*   dst   = (const int*)d_in[1];
  const int*   t     = (const int*)d_in[2];
  const float* msg   = (const float*)d_in[3];
  const float* price = (const float*)d_in[4];
  const int*   xst   = (const int*)d_in[6];
  const float* memory= (const float*)d_in[7];
  const float* lu    = (const float*)d_in[8];
  const float* w_t   = (const float*)d_in[9];
  const float* b_t   = (const float*)d_in[10];
  const float* W_ih  = (const float*)d_in[11];
  const float* b_ih  = (const float*)d_in[12];
  const float* W_hh  = (const float*)d_in[13];
  const float* b_hh  = (const float*)d_in[14];
  const float* party = (const float*)d_in[15];
  const float* state = (const float*)d_in[16];
  const float* W_sp  = (const float*)d_in[17];
  const float* b_sp  = (const float*)d_in[18];
  const float* W_ihl = (const float*)d_in[19];
  const float* W_hhl = (const float*)d_in[20];
  const float* b_ihl = (const float*)d_in[21];
  const float* b_hhl = (const float*)d_in[22];
  const float* W_pp  = (const float*)d_in[23];
  const float* b_pp  = (const float*)d_in[24];
  const float* W1    = (const float*)d_in[25];
  const float* b1    = (const float*)d_in[26];
  const float* W2    = (const float*)d_in[27];
  const float* b2    = (const float*)d_in[28];
  float* out = (float*)d_out;

  if (ws_size < WS_NEED) {
    (void)hipMemsetAsync(d_out, 0, (size_t)out_size*4, stream);
    return;
  }

  char* ws = (char*)d_ws;
  u64*   key  = (u64*)(ws + OFF_KEY);
  int*   cnt  = (int*)(ws + OFF_CNT);
  int*   list = (int*)(ws + OFF_LIST);
  float* uv   = (float*)(ws + OFF_UV);
  float* hn   = (float*)(ws + OFF_HN);
  float* A    = (float*)(ws + OFF_A);
  float* B    = (float*)(ws + OFF_B);
  float* c0   = (float*)(ws + OFF_C0);
  short* Wbf  = (short*)(ws + OFF_WBF);

  (void)hipMemsetAsync(ws, 0, OFF_LIST, stream);
  k_scatter<<<(NE+255)/256, 256, 0, stream>>>(src, dst, t, key);
  k_compact<<<(NN+255)/256, 256, 0, stream>>>(key, list, cnt);
  k_pre<<<17, 256, 0, stream>>>(W1, W_sp, W_pp, b_sp, b_pp, b1, A, B, c0);
  k_prew<<<116, 256, 0, stream>>>(W_ih, W_hh, W1, Wbf);
  k_gl<<<LSTB + GRUB, 512, 0, stream>>>(key, list, cnt, src, dst, t, msg, memory, lu,
                                        w_t, b_t, Wbf, b_ih, b_hh, uv,
                                        price, W_ihl, W_hhl, b_ihl, b_hhl, hn);
  k_final<<<(NE+255)/256, 256, 0, stream>>>(src, dst, xst, party, state, uv, hn,
                                            A, B, c0, W2, b2, out);
}

// Round 23
// 443.990 us; speedup vs baseline: 1.1427x; 1.1427x over previous
//
#include <hip/hip_runtime.h>
#include <stdint.h>

#define NN    200000
#define NE    100000
#define HD    128
#define EFD   64
#define NG    384

typedef unsigned long long u64;
typedef short bf16x8 __attribute__((ext_vector_type(8)));
typedef float f32x4  __attribute__((ext_vector_type(4)));

#define OFF_KEY   ((size_t)0)
#define OFF_CNT   ((size_t)1600000)
#define OFF_LIST  ((size_t)1600256)
#define OFF_UV    ((size_t)2400256)
#define OFF_HN    ((size_t)104800256)
#define OFF_A     ((size_t)117600256)
#define OFF_B     ((size_t)117608448)
#define OFF_C0    ((size_t)117616640)
#define OFF_WBF   ((size_t)117616896)
#define WS_NEED   ((size_t)118092032)

#define W1OFF 221184
#define GRUB  3128      // GRU virtual blocks (>= ceil(cnt/64) worst case 3125)
#define LSTB  782       // LSTM blocks (128 edges each)

__device__ __forceinline__ float frcp(float x){ return __builtin_amdgcn_rcpf(x); }
__device__ __forceinline__ float sigf(float x){ return frcp(1.f + __expf(-x)); }
__device__ __forceinline__ float tanhf_(float x){ return 1.f - 2.f*frcp(__expf(2.f*x) + 1.f); }
__device__ __forceinline__ float4 ld4(const float* p){ return *reinterpret_cast<const float4*>(p); }

__device__ __forceinline__ short f2bf(float f){
  unsigned u = __float_as_uint(f);
  u += 0x7fffu + ((u>>16)&1u);
  return (short)(u>>16);
}
__device__ __forceinline__ unsigned cvtpk(float lo, float hi){
  unsigned r;
  asm("v_cvt_pk_bf16_f32 %0, %1, %2" : "=v"(r) : "v"(lo), "v"(hi));
  return r;
}
__device__ __forceinline__ void gl16(const void* g, void* l) {
  __builtin_amdgcn_global_load_lds(
      (const __attribute__((address_space(1))) void*)g,
      (__attribute__((address_space(3))) void*)l, 16, 0, 0);
}

__global__ void k_scatter(const int* __restrict__ src, const int* __restrict__ dst,
                          const int* __restrict__ t, u64* __restrict__ key) {
  int e = blockIdx.x*256 + threadIdx.x;
  if (e >= NE) return;
  u64 tt = (u64)(unsigned)(t[e] + 1);
  atomicMax(&key[src[e]], (tt<<18) | (u64)(unsigned)e);
  atomicMax(&key[dst[e]], (tt<<18) | (1ULL<<17) | (u64)(unsigned)e);
}

__global__ void k_compact(const u64* __restrict__ key, int* __restrict__ list,
                          int* __restrict__ count) {
  int n = blockIdx.x*256 + threadIdx.x;
  if (n >= NN) return;
  if (key[n] != 0ULL) { int p = atomicAdd(count, 1); list[p] = n; }
}

__global__ void k_pre(const float* __restrict__ W1, const float* __restrict__ W_sp,
                      const float* __restrict__ W_pp, const float* __restrict__ b_sp,
                      const float* __restrict__ b_pp, const float* __restrict__ b1,
                      float* __restrict__ A, float* __restrict__ B, float* __restrict__ c0)
{
  int tid = blockIdx.x*256 + threadIdx.x;
  if (tid < 2048) {
    int o = tid >> 5, j = tid & 31;
    float s = 0.f;
    for (int k = 0; k < 128; ++k) s = fmaf(W1[o*NG + k], W_sp[k*32 + j], s);
    A[tid] = s;
  } else if (tid < 4096) {
    int q = tid - 2048;
    int o = q >> 5, j = q & 31;
    float s = 0.f;
    for (int k = 0; k < 128; ++k)
      s = fmaf(W1[o*NG + 128 + k] + W1[o*NG + 256 + k], W_pp[k*32 + j], s);
    B[q] = s;
  } else if (tid < 4160) {
    int o = tid - 4096;
    float s = b1[o];
    for (int k = 0; k < 128; ++k) {
      s = fmaf(W1[o*NG + k], b_sp[k], s);
      s = fmaf(W1[o*NG + 128 + k] + W1[o*NG + 256 + k], b_pp[k], s);
    }
    c0[o] = s;
  }
}

__global__ void k_prew(const float* __restrict__ W_ih, const float* __restrict__ W_hh,
                       const float* __restrict__ W1, short* __restrict__ Wbf)
{
  int idx = blockIdx.x*256 + threadIdx.x;
  if (idx < 9*384*8) {
    int s   = idx & 7;
    int n   = (idx >> 3) % 384;
    int ch9 = idx / (384*8);
    int k8  = s ^ (n & 7);
    int k   = ch9*64 + k8*8;
    short v[8];
    #pragma unroll
    for (int e = 0; e < 8; ++e) {
      int kk = k + e;
      float f = (kk < 448) ? W_ih[(size_t)n*448 + kk] : W_hh[(size_t)n*HD + (kk-448)];
      v[e] = f2bf(f);
    }
    *reinterpret_cast<bf16x8*>(Wbf + (size_t)ch9*24576 + n*64 + s*8) =
        *reinterpret_cast<bf16x8*>(v);
  } else if (idx < 9*384*8 + 128*16) {
    int idx2 = idx - 9*384*8;
    int s = idx2 & 15, r = idx2 >> 4;
    int k8 = s ^ (r & 15);
    int k = k8*8;
    short v[8];
    #pragma unroll
    for (int e = 0; e < 8; ++e) {
      int kk = k + e;
      float f = (r < 64) ? W1[(size_t)r*NG + kk] : W1[(size_t)(r-64)*NG + 128 + kk];
      v[e] = f2bf(f);
    }
    *reinterpret_cast<bf16x8*>(Wbf + W1OFF + r*128 + s*8) =
        *reinterpret_cast<bf16x8*>(v);
  }
}

// ---------- FUSED GRU + LSTM: 512 thr; longest-job-first: bid<LSTB -> LSTM ----------
__global__ __launch_bounds__(512, 2) void k_gl(
    const u64* __restrict__ key, const int* __restrict__ list, const int* __restrict__ count,
    const int* __restrict__ src, const int* __restrict__ dst, const int* __restrict__ t,
    const float* __restrict__ msg, const float* __restrict__ memory,
    const float* __restrict__ last_update,
    const float* __restrict__ w_t, const float* __restrict__ b_t,
    const short* __restrict__ Wbf, const float* __restrict__ b_ih,
    const float* __restrict__ b_hh, float* __restrict__ uv,
    const float* __restrict__ price, const float* __restrict__ W_ihl,
    const float* __restrict__ W_hhl, const float* __restrict__ b_ihl,
    const float* __restrict__ b_hhl, float* __restrict__ hn_out)
{
  __shared__ char lds[60416];    // arena, carved per role
  int bid = blockIdx.x;
  int tid = threadIdx.x;
  int wid = tid >> 6, lane = tid & 63;
  int lr = lane & 15, lk = lane >> 4;

  if (bid >= LSTB) {
    // ================= GRU role (virtual block g) =================
    int g = bid - LSTB;
    short* Wsb   = reinterpret_cast<short*>(lds);            // 48KB
    short* Xsb   = reinterpret_cast<short*>(lds + 49152);    // 8KB
    float* bias4 = reinterpret_cast<float*>(lds + 57344);    // 2KB
    int*   sn_self  = reinterpret_cast<int*>(lds + 59392);
    int*   sn_other = reinterpret_cast<int*>(lds + 59648);
    int*   sn_e     = reinterpret_cast<int*>(lds + 59904);
    float* sn_dt    = reinterpret_cast<float*>(lds + 60160);
    short* Mn2 = &Wsb[16384];

    int cnt = count[0];
    int base = g * 64;
    if (base >= cnt) return;

    if (tid < 64) {
      int idx = base + tid;
      int cl = idx < cnt ? idx : (cnt - 1);
      int n = list[cl];
      u64 k = key[n];
      int e   = (int)(k & 0x1FFFFULL);
      int isd = (int)((k >> 17) & 1ULL);
      sn_self[tid]  = n;
      sn_other[tid] = isd ? src[e] : dst[e];
      sn_e[tid]     = e;
      sn_dt[tid]    = (float)t[e] - last_update[n];
    }
    if (tid < 128) {
      int h = tid;
      bias4[h]       = b_ih[h]       + b_hh[h];
      bias4[128 + h] = b_ih[128 + h] + b_hh[128 + h];
      bias4[256 + h] = b_ih[256 + h];
      bias4[384 + h] = b_hh[256 + h];
    }
    __syncthreads();

    f32x4 aR[4], aZ[4], aNX[4], aNM[4];
    #pragma unroll
    for (int mt = 0; mt < 4; ++mt) { aR[mt] = (f32x4)0.f; aZ[mt] = (f32x4)0.f;
                                     aNX[mt] = (f32x4)0.f; aNM[mt] = (f32x4)0.f; }

    int node8 = tid >> 3, k8s = tid & 7;

    float4 xA0, xB0, xA1, xB1, xA2, xB2, xA3, xB3, xA4, xB4;
    {
      const float* pSelf  = memory + (size_t)sn_self[node8]*HD  + k8s*8;
      const float* pOther = memory + (size_t)sn_other[node8]*HD + k8s*8;
      const float* pMsg   = msg + (size_t)sn_e[node8]*EFD + k8s*8;
      xA0 = ld4(pSelf);       xB0 = ld4(pSelf+4);
      xA1 = ld4(pSelf+64);    xB1 = ld4(pSelf+68);
      xA2 = ld4(pOther);      xB2 = ld4(pOther+4);
      xA3 = ld4(pOther+64);   xB3 = ld4(pOther+68);
      xA4 = ld4(pMsg);        xB4 = ld4(pMsg+4);
    }

    constexpr int WCH[9] = {0, 7, 1, 8, 2, 3, 4, 5, 6};
    constexpr int XST[9] = {0,-1, 1,-1, 2, 3, 4,-2,-2};

    int hrow = wid*16 + lr;
    int swzH = (hrow & 7);

    #pragma unroll
    for (int p = 0; p < 9; ++p) {
      const int W = WCH[p];
      #pragma unroll
      for (int i = 0; i < 6; ++i) {
        int q = i*512 + tid;
        gl16(Wbf + (size_t)W*24576 + q*8, &Wsb[q*8]);
      }
      if (XST[p] >= 0) {
        float4 fa, fb;
        switch (XST[p]) {
          case 0: fa = xA0; fb = xB0; break;
          case 1: fa = xA1; fb = xB1; break;
          case 2: fa = xA2; fb = xB2; break;
          case 3: fa = xA3; fb = xB3; break;
          default: fa = xA4; fb = xB4; break;
        }
        short xs[8];
        xs[0]=f2bf(fa.x); xs[1]=f2bf(fa.y); xs[2]=f2bf(fa.z); xs[3]=f2bf(fa.w);
        xs[4]=f2bf(fb.x); xs[5]=f2bf(fb.y); xs[6]=f2bf(fb.z); xs[7]=f2bf(fb.w);
        *reinterpret_cast<bf16x8*>(&Xsb[node8*64 + ((k8s ^ (node8&7))<<3)]) =
            *reinterpret_cast<bf16x8*>(xs);
      } else if (XST[p] == -2) {
        int kk = (W == 6 ? 64 : 0) + k8s*8;
        float dt = sn_dt[node8];
        short xs[8];
        #pragma unroll
        for (int q = 0; q < 8; ++q) xs[q] = f2bf(cosf(fmaf(dt, w_t[kk+q], b_t[kk+q])));
        *reinterpret_cast<bf16x8*>(&Xsb[node8*64 + ((k8s ^ (node8&7))<<3)]) =
            *reinterpret_cast<bf16x8*>(xs);
      }
      __syncthreads();

      #pragma unroll
      for (int ks = 0; ks < 2; ++ks) {
        int k8 = ks*4 + lk;
        int so = (k8 ^ swzH) << 3;
        bf16x8 bR = *reinterpret_cast<const bf16x8*>(&Wsb[(size_t)hrow*64 + so]);
        bf16x8 bZ = *reinterpret_cast<const bf16x8*>(&Wsb[(size_t)(128+hrow)*64 + so]);
        bf16x8 bN = *reinterpret_cast<const bf16x8*>(&Wsb[(size_t)(256+hrow)*64 + so]);
        #pragma unroll
        for (int mt = 0; mt < 4; ++mt) {
          int anode = mt*16 + lr;
          bf16x8 a = *reinterpret_cast<const bf16x8*>(&Xsb[anode*64 + ((k8 ^ (anode&7))<<3)]);
          aR[mt] = __builtin_amdgcn_mfma_f32_16x16x32_bf16(a, bR, aR[mt], 0, 0, 0);
          aZ[mt] = __builtin_amdgcn_mfma_f32_16x16x32_bf16(a, bZ, aZ[mt], 0, 0, 0);
          if (W < 7) aNX[mt] = __builtin_amdgcn_mfma_f32_16x16x32_bf16(a, bN, aNX[mt], 0, 0, 0);
          else       aNM[mt] = __builtin_amdgcn_mfma_f32_16x16x32_bf16(a, bN, aNM[mt], 0, 0, 0);
        }
      }
      __syncthreads();
    }

    #pragma unroll
    for (int i = 0; i < 4; ++i) {
      int q = i*512 + tid;
      gl16(Wbf + W1OFF + q*8, &Wsb[q*8]);
    }

    {
      int h = hrow;
      int k8h = h >> 3, eh = h & 7;
      float br_ = bias4[h], bz_ = bias4[128+h], bnx_ = bias4[256+h], bnm_ = bias4[384+h];
      #pragma unroll
      for (int mt = 0; mt < 4; ++mt) {
        #pragma unroll
        for (int i = 0; i < 4; ++i) {
          int node = mt*16 + lk*4 + i;
          float r  = sigf(aR[mt][i] + br_);
          float z  = sigf(aZ[mt][i] + bz_);
          float nv = tanhf_(aNX[mt][i] + bnx_ + r*(aNM[mt][i] + bnm_));
          float m  = memory[(size_t)sn_self[node]*HD + h];
          Mn2[node*128 + ((k8h ^ (node&15))<<3) + eh] = f2bf((1.f - z)*nv + z*m);
        }
      }
    }
    __syncthreads();

    {
      int orow = wid*16 + lr;
      f32x4 acc2[4];
      #pragma unroll
      for (int mt = 0; mt < 4; ++mt) acc2[mt] = (f32x4)0.f;
      #pragma unroll
      for (int kf = 0; kf < 4; ++kf) {
        int k8 = kf*4 + lk;
        bf16x8 b = *reinterpret_cast<const bf16x8*>(&Wsb[orow*128 + ((k8 ^ (orow&15))<<3)]);
        #pragma unroll
        for (int mt = 0; mt < 4; ++mt) {
          int anode = mt*16 + lr;
          bf16x8 a = *reinterpret_cast<const bf16x8*>(&Mn2[anode*128 + ((k8 ^ (anode&15))<<3)]);
          acc2[mt] = __builtin_amdgcn_mfma_f32_16x16x32_bf16(a, b, acc2[mt], 0, 0, 0);
        }
      }
      #pragma unroll
      for (int mt = 0; mt < 4; ++mt) {
        #pragma unroll
        for (int i = 0; i < 4; ++i) {
          int node = mt*16 + lk*4 + i;
          if (base + node < cnt)
            uv[(size_t)sn_self[node]*128 + orow] = acc2[mt][i];
        }
      }
    }
  } else {
    // ================= LSTM role (block l = bid, 128 edges, 8 waves) =================
    int l = bid;
    short* Wb   = reinterpret_cast<short*>(lds);             // 8KB
    float* ps   = reinterpret_cast<float*>(lds + 8192);      // 25.6KB
    float* hbuf = reinterpret_cast<float*>(lds + 33792);     // 18.4KB (8 x 576)

    {
      int base = tid * 8;
      #pragma unroll
      for (int q = 0; q < 4; ++q) {
        unsigned pk = cvtpk(W_hhl[base + q*2], W_hhl[base + q*2 + 1]);
        reinterpret_cast<unsigned*>(Wb)[tid*4 + q] = pk;
      }
    }
    int ebase = l * 128;
    int m = NE - ebase; if (m > 128) m = 128;
    for (int i = tid; i < 128*50; i += 512) {
      int r = i / 50, cidx = i % 50;
      int rr = r < m ? r : m - 1;
      ps[i] = price[(size_t)(ebase + rr)*50 + cidx];
    }
    __syncthreads();

    bf16x8 bw[8];
    float wih8[8], bias8[8];
    #pragma unroll
    for (int tI = 0; tI < 8; ++tI) {
      int row = tI*16 + lr;
      bw[tI] = *reinterpret_cast<const bf16x8*>(&Wb[row*32 + lk*8]);
      wih8[tI] = W_ihl[row];
      bias8[tI] = b_ihl[row] + b_hhl[row];
    }

    int we = wid * 16;
    float* hb = hbuf + wid*576;

    float c8[4][2];
    #pragma unroll
    for (int i = 0; i < 4; ++i) { c8[i][0] = 0.f; c8[i][1] = 0.f; }
    bf16x8 afrag = {0,0,0,0,0,0,0,0};

    #pragma unroll 1
    for (int s = 0; s < 50; ++s) {
      float xv[4];
      #pragma unroll
      for (int i = 0; i < 4; ++i) xv[i] = ps[(we + lk*4 + i)*50 + s];
      f32x4 acc[8];
      #pragma unroll
      for (int tI = 0; tI < 8; ++tI) {
        f32x4 ci;
        #pragma unroll
        for (int i = 0; i < 4; ++i) ci[i] = fmaf(xv[i], wih8[tI], bias8[tI]);
        acc[tI] = __builtin_amdgcn_mfma_f32_16x16x32_bf16(afrag, bw[tI], ci, 0, 0, 0);
      }
      #pragma unroll
      for (int i = 0; i < 4; ++i) {
        #pragma unroll
        for (int p = 0; p < 2; ++p) {
          float ei = __expf(-acc[0+p][i]);
          float ef = __expf(-acc[2+p][i]);
          float eg = __expf(2.f*acc[4+p][i]);
          float eo = __expf(-acc[6+p][i]);
          float di = 1.f + ei, df_ = 1.f + ef, dg = eg + 1.f, do_ = 1.f + eo;
          float m1 = di*df_, m2 = do_*dg;
          float R  = frcp(m1*m2);
          float ig = R*df_*m2;
          float fg = R*di*m2;
          float og = R*m1*dg;
          float gg = fmaf(-2.f, R*m1*do_, 1.f);
          c8[i][p] = fmaf(fg, c8[i][p], ig*gg);
          float th = 1.f - 2.f*frcp(__expf(2.f*c8[i][p]) + 1.f);
          hb[(lk*4 + i)*36 + p*16 + lr] = og*th;
        }
      }
      asm volatile("s_waitcnt lgkmcnt(0)" ::: "memory");
      float4 h0 = *reinterpret_cast<const float4*>(&hb[lr*36 + lk*8]);
      float4 h1 = *reinterpret_cast<const float4*>(&hb[lr*36 + lk*8 + 4]);
      unsigned pk_[4];
      pk_[0] = cvtpk(h0.x, h0.y);
      pk_[1] = cvtpk(h0.z, h0.w);
      pk_[2] = cvtpk(h1.x, h1.y);
      pk_[3] = cvtpk(h1.z, h1.w);
      afrag = *reinterpret_cast<bf16x8*>(pk_);
    }

    int e_g = ebase + we + lr;
    if (e_g < NE) {
      float4 h0 = *reinterpret_cast<const float4*>(&hb[lr*36 + lk*8]);
      float4 h1 = *reinterpret_cast<const float4*>(&hb[lr*36 + lk*8 + 4]);
      *reinterpret_cast<float4*>(hn_out + (size_t)e_g*32 + lk*8)     = h0;
      *reinterpret_cast<float4*>(hn_out + (size_t)e_g*32 + lk*8 + 4) = h1;
    }
  }
}

// ---------- fused output ----------
__global__ __launch_bounds__(256) void k_final(
    const int* __restrict__ src, const int* __restrict__ dst, const int* __restrict__ xst,
    const float* __restrict__ party, const float* __restrict__ state,
    const float* __restrict__ uv, const float* __restrict__ hn,
    const float* __restrict__ A, const float* __restrict__ B, const float* __restrict__ c0,
    const float* __restrict__ W2, const float* __restrict__ b2, float* __restrict__ out)
{
  __shared__ float As[2048], Bs[2048], c0s[64], W2s[64];
  int tid = threadIdx.x;
  for (int i = tid; i < 2048; i += 256) { As[i] = A[i]; Bs[i] = B[i]; }
  if (tid < 64) { c0s[tid] = c0[tid]; W2s[tid] = W2[tid]; }
  __syncthreads();
  int e = blockIdx.x*256 + tid;
  if (e >= NE) return;
  int s = src[e], d = dst[e];
  int p = xst[2*s], stt = xst[2*s + 1];
  float4 sf4[8], hv4[8];
  #pragma unroll
  for (int i = 0; i < 4; ++i) sf4[i]   = ld4(party + p*16 + i*4);
  #pragma unroll
  for (int i = 0; i < 4; ++i) sf4[4+i] = ld4(state + stt*16 + i*4);
  #pragma unroll
  for (int i = 0; i < 8; ++i) hv4[i] = ld4(hn + (size_t)e*32 + i*4);
  const float* urow = uv + (size_t)s*128;
  const float* vrow = uv + (size_t)d*128 + 64;
  float oacc = b2[0];
  #pragma unroll 4
  for (int o4 = 0; o4 < 16; ++o4) {
    float4 u4 = ld4(urow + o4*4);
    float4 v4 = ld4(vrow + o4*4);
    float4 cc = *reinterpret_cast<const float4*>(&c0s[o4*4]);
    float4 w2 = *reinterpret_cast<const float4*>(&W2s[o4*4]);
    float hh[4] = {u4.x+v4.x+cc.x, u4.y+v4.y+cc.y, u4.z+v4.z+cc.z, u4.w+v4.w+cc.w};
    #pragma unroll
    for (int oo = 0; oo < 4; ++oo) {
      int o = o4*4 + oo;
      float acc = hh[oo];
      #pragma unroll
      for (int j4 = 0; j4 < 8; ++j4) {
        float4 a = *reinterpret_cast<const float4*>(&As[o*32 + j4*4]);
        float4 b = *reinterpret_cast<const float4*>(&Bs[o*32 + j4*4]);
        float4 sfv = sf4[j4], hvv = hv4[j4];
        acc = fmaf(a.x,sfv.x, fmaf(a.y,sfv.y, fmaf(a.z,sfv.z, fmaf(a.w,sfv.w, acc))));
        acc = fmaf(b.x,hvv.x, fmaf(b.y,hvv.y, fmaf(b.z,hvv.z, fmaf(b.w,hvv.w, acc))));
      }
      float w2v = (oo==0) ? w2.x : (oo==1) ? w2.y : (oo==2) ? w2.z : w2.w;
      oacc = fmaf(w2v, fmaxf(acc, 0.f), oacc);
    }
  }
  out[e] = oacc;
}

extern "C" void kernel_launch(void* const* d_in, const int* in_sizes, int n_in,
                              void* d_out, int out_size, void* d_ws, size_t ws_size,
                              hipStream_t stream) {
  const int*   src   = (const int*)d_in[0];
  const int*   dst   = (const int*)d_in[1];
  const int*   t     = (const int*)d_in[2];
  const float* msg   = (const float*)d_in[3];
  const float* price = (const float*)d_in[4];
  const int*   xst   = (const int*)d_in[6];
  const float* memory= (const float*)d_in[7];
  const float* lu    = (const float*)d_in[8];
  const float* w_t   = (const float*)d_in[9];
  const float* b_t   = (const float*)d_in[10];
  const float* W_ih  = (const float*)d_in[11];
  const float* b_ih  = (const float*)d_in[12];
  const float* W_hh  = (const float*)d_in[13];
  const float* b_hh  = (const float*)d_in[14];
  const float* party = (const float*)d_in[15];
  const float* state = (const float*)d_in[16];
  const float* W_sp  = (const float*)d_in[17];
  const float* b_sp  = (const float*)d_in[18];
  const float* W_ihl = (const float*)d_in[19];
  const float* W_hhl = (const float*)d_in[20];
  const float* b_ihl = (const float*)d_in[21];
  const float* b_hhl = (const float*)d_in[22];
  const float* W_pp  = (const float*)d_in[23];
  const float* b_pp  = (const float*)d_in[24];
  const float* W1    = (const float*)d_in[25];
  const float* b1    = (const float*)d_in[26];
  const float* W2    = (const float*)d_in[27];
  const float* b2    = (const float*)d_in[28];
  float* out = (float*)d_out;

  if (ws_size < WS_NEED) {
    (void)hipMemsetAsync(d_out, 0, (size_t)out_size*4, stream);
    return;
  }

  char* ws = (char*)d_ws;
  u64*   key  = (u64*)(ws + OFF_KEY);
  int*   cnt  = (int*)(ws + OFF_CNT);
  int*   list = (int*)(ws + OFF_LIST);
  float* uv   = (float*)(ws + OFF_UV);
  float* hn   = (float*)(ws + OFF_HN);
  float* A    = (float*)(ws + OFF_A);
  float* B    = (float*)(ws + OFF_B);
  float* c0   = (float*)(ws + OFF_C0);
  short* Wbf  = (short*)(ws + OFF_WBF);

  (void)hipMemsetAsync(ws, 0, OFF_LIST, stream);
  k_scatter<<<(NE+255)/256, 256, 0, stream>>>(src, dst, t, key);
  k_compact<<<(NN+255)/256, 256, 0, stream>>>(key, list, cnt);
  k_pre<<<17, 256, 0, stream>>>(W1, W_sp, W_pp, b_sp, b_pp, b1, A, B, c0);
  k_prew<<<116, 256, 0, stream>>>(W_ih, W_hh, W1, Wbf);
  k_gl<<<LSTB + GRUB, 512, 0, stream>>>(key, list, cnt, src, dst, t, msg, memory, lu,
                                        w_t, b_t, Wbf, b_ih, b_hh, uv,
                                        price, W_ihl, W_hhl, b_ihl, b_hhl, hn);
  k_final<<<(NE+255)/256, 256, 0, stream>>>(src, dst, xst, party, state, uv, hn,
                                            A, B, c0, W2, b2, out);
}